// Round 7
// baseline (163.776 us; speedup 1.0000x reference)
//
#include <hip/hip_runtime.h>
#include <hip/hip_bf16.h>

typedef unsigned short u16;
typedef unsigned int u32;

#define TT 192
#define BB 2
#define HH 8
#define DD 64
#define CC 512
#define MM (BB*TT)   // 384
#define KG 4         // k-values per attention block (768 blocks = 3/CU exact)

// ws layout (u16 elements): Q,K0,K1,V0,V1 each [bh][t][d], then ATT [m][c]
#define TSZ   ((size_t)MM * CC)
#define OFF_ATT (5 * TSZ)

typedef short bf16x8 __attribute__((ext_vector_type(8)));
typedef float f32x4  __attribute__((ext_vector_type(4)));

union FragU { uint4 u; bf16x8 b; };

// Raw HW transcendentals (r13-verified: VALUBusy 58->27%)
#if __has_builtin(__builtin_amdgcn_exp2f)
#define EXP2F(x) __builtin_amdgcn_exp2f(x)
#else
#define EXP2F(x) exp2f(x)
#endif
#if __has_builtin(__builtin_amdgcn_rcpf)
#define RCPF(x) __builtin_amdgcn_rcpf(x)
#else
#define RCPF(x) (1.f / (x))
#endif

__device__ __forceinline__ float bf2f(u16 u) {
    return __uint_as_float(((u32)u) << 16);
}
__device__ __forceinline__ u16 f2bf(float f) {
    u32 u = __float_as_uint(f);
    u32 r = u + 0x7FFFu + ((u >> 16) & 1u);   // RNE
    return (u16)(r >> 16);
}
// pack hi16(a),hi16(b) -> one u32 (truncation round; bias cancels in P/Z)
__device__ __forceinline__ u32 trunc_pk(u32 b_hi, u32 a_lo) {
    return __builtin_amdgcn_perm(b_hi, a_lo, 0x07060302u);
}

// dtype detect: 1 load + ballot. bf16 data => low u16 exponent near 127.
__device__ __forceinline__ u32 detect_bf16_fast(const u32* __restrict__ x) {
    const int lane = threadIdx.x & 63;
    u32 v = x[lane & 31];
    u32 e = (v >> 7) & 0xFF;
    unsigned long long m = __ballot(e >= 113 && e <= 133);
    return (__popcll(m) >= 32) ? 1u : 0u;
}

// dtype-aware 16-element load (two uint4 of packed bf16)
__device__ __forceinline__ void ld16(const void* __restrict__ base, size_t off, u32 fl,
                                     uint4& lo, uint4& hi) {
    if (fl) {
        const uint4* p = (const uint4*)((const u16*)base + off);
        lo = p[0]; hi = p[1];
    } else {
        const float* s = (const float*)base + off;
        float4 f0 = *(const float4*)(s);
        float4 f1 = *(const float4*)(s + 4);
        float4 f2 = *(const float4*)(s + 8);
        float4 f3 = *(const float4*)(s + 12);
        lo = make_uint4((u32)f2bf(f0.x) | ((u32)f2bf(f0.y) << 16),
                        (u32)f2bf(f0.z) | ((u32)f2bf(f0.w) << 16),
                        (u32)f2bf(f1.x) | ((u32)f2bf(f1.y) << 16),
                        (u32)f2bf(f1.z) | ((u32)f2bf(f1.w) << 16));
        hi = make_uint4((u32)f2bf(f2.x) | ((u32)f2bf(f2.y) << 16),
                        (u32)f2bf(f2.z) | ((u32)f2bf(f2.w) << 16),
                        (u32)f2bf(f3.x) | ((u32)f2bf(f3.y) << 16),
                        (u32)f2bf(f3.z) | ((u32)f2bf(f3.w) << 16));
    }
}

// ---------------------------------------------------------------------------
// LDS-staged MFMA projection GEMM (r9-verified): out = A @ W^T + bias.
// ---------------------------------------------------------------------------
__device__ __forceinline__ void proj_lds(const void* __restrict__ A, u32 aFl,
                                         const void* __restrict__ W,
                                         const void* __restrict__ bias, u32 wFl,
                                         void* __restrict__ out, int headperm, u32 outFl) {
    __shared__ __align__(16) u16 As[64][72];
    __shared__ __align__(16) u16 Ws[64][72];
    const int tid = threadIdx.x;
    const int w = tid >> 6, lane = tid & 63;
    const int quad = lane >> 4, li = lane & 15;
    const int mb = blockIdx.y * 64, nb = blockIdx.x * 64;

    const int r = tid >> 2;
    const int c = (tid & 3) * 16;

    const size_t abase = (size_t)(mb + r) * CC + c;
    const size_t wbase = (size_t)(nb + r) * CC + c;

    f32x4 acc[4];
#pragma unroll
    for (int ct = 0; ct < 4; ct++) acc[ct] = (f32x4){0.f, 0.f, 0.f, 0.f};

    uint4 a0, a1, w0, w1;
    ld16(A, abase, aFl, a0, a1);
    ld16(W, wbase, wFl, w0, w1);

#pragma unroll
    for (int step = 0; step < 8; step++) {
        *(uint4*)&As[r][c] = a0; *(uint4*)&As[r][c + 8] = a1;
        *(uint4*)&Ws[r][c] = w0; *(uint4*)&Ws[r][c + 8] = w1;
        __syncthreads();
        if (step < 7) {
            const int kb = (step + 1) * 64;
            ld16(A, abase + kb, aFl, a0, a1);
            ld16(W, wbase + kb, wFl, w0, w1);
        }
#pragma unroll
        for (int kk = 0; kk < 2; kk++) {
            FragU af; af.u = *(const uint4*)&As[w * 16 + li][kk * 32 + quad * 8];
#pragma unroll
            for (int ct = 0; ct < 4; ct++) {
                FragU wf; wf.u = *(const uint4*)&Ws[ct * 16 + li][kk * 32 + quad * 8];
                acc[ct] = __builtin_amdgcn_mfma_f32_16x16x32_bf16(af.b, wf.b, acc[ct], 0, 0, 0);
            }
        }
        __syncthreads();
    }

#pragma unroll
    for (int ct = 0; ct < 4; ct++) {
        const int n = nb + ct * 16 + li;
        const float bv = wFl ? bf2f(((const u16*)bias)[n]) : ((const float*)bias)[n];
#pragma unroll
        for (int rr = 0; rr < 4; rr++) {
            const int m = mb + w * 16 + quad * 4 + rr;
            const float v = acc[ct][rr] + bv;
            if (headperm) {
                const int b = (m >= TT) ? 1 : 0;
                const int tloc = m - b * TT;
                ((u16*)out)[((size_t)(b * HH + (n >> 6)) * TT + tloc) * DD + (n & 63)] = f2bf(v);
            } else {
                if (outFl) ((u16*)out)[(size_t)m * CC + n] = f2bf(v);
                else       ((float*)out)[(size_t)m * CC + n] = v;
            }
        }
    }
}

__global__ __launch_bounds__(256) void proj5_kernel(
    const void* __restrict__ x,
    const void* __restrict__ Wq,  const void* __restrict__ bq,
    const void* __restrict__ Wk0, const void* __restrict__ bk0,
    const void* __restrict__ Wk1, const void* __restrict__ bk1,
    const void* __restrict__ Wv0, const void* __restrict__ bv0,
    const void* __restrict__ Wv1, const void* __restrict__ bv1,
    u16* __restrict__ ws16) {
    const u32 fl = detect_bf16_fast((const u32*)x);
    const int z = blockIdx.z;
    const void* W; const void* bi;
    switch (z) {
        case 0:  W = Wq;  bi = bq;  break;
        case 1:  W = Wk0; bi = bk0; break;
        case 2:  W = Wk1; bi = bk1; break;
        case 3:  W = Wv0; bi = bv0; break;
        default: W = Wv1; bi = bv1; break;
    }
    proj_lds(x, fl, W, bi, fl, (void*)(ws16 + (size_t)z * TSZ), 1, 1u);
}

__global__ __launch_bounds__(256) void projo_kernel(const u16* __restrict__ ws16,
                                                    const void* __restrict__ Wo,
                                                    const void* __restrict__ bo,
                                                    void* __restrict__ out,
                                                    const void* __restrict__ xorig) {
    const u32 fl = detect_bf16_fast((const u32*)xorig);
    proj_lds(ws16 + OFF_ATT, 1u, Wo, bo, fl, out, 0, fl);
}

// ---------------------------------------------------------------------------
// MFMA attention, r20: r18 base (KG=4, 3 blocks/CU, LDS-resident swizzled k1,
// amortized v1t, register-resident P) minus the two remaining k-loop stalls:
//  1. v0 HOISTED out of the k loop: 48 k-invariant bf16 values loaded once
//     per block during staging, packed 2/u32 into 24 VGPRs; per-k unpack is
//     1 VALU op each (<<16 / &0xFFFF0000). Removes 144 of 192 global loads
//     per wave (each ~200cy L2, previously on the epilogue serial chain).
//  2. BARRIER-FREE k loop: per-(k,wave) private osum[KG][4][64] slice (4KB,
//     race-free), zero barriers inside the loop; ONE __syncthreads after,
//     then fused reduce+store (256 thr = KG*64 outputs). Barriers 5 -> 2;
//     waves drift across k-iterations so residual stalls overlap.
// r19 lesson folded in: no lockstep, no cross-wave exchange.
// LDS: k1L 24576 + v1t 25600 + osum 4096 = 54272 B <= 54613 -> 3 blocks/CU.
// VGPR ~150 expected (registers buy ILP here, not occupancy -- r15).
// ---------------------------------------------------------------------------
__global__ __launch_bounds__(256) void attn_kernel(u16* __restrict__ ws16) {
    __shared__ __align__(16) u16 k1L[TT * DD];      // 24576 B, XOR-swizzled
    __shared__ __align__(16) u16 v1t[DD * 200];     // 25600 B, r14 layout
    __shared__ float osum[KG][4][64];               // 4096 B, per-(k,wave)
    const int tid = threadIdx.x;
    const int w = tid >> 6, lane = tid & 63;
    const int quad = lane >> 4, li = lane & 15;
    const int kbase = blockIdx.x * KG, bh = blockIdx.y;

    const u16* qg0 = ws16 + ((size_t)bh * TT) * DD;
    const u16* k0g = ws16 + TSZ     + (size_t)bh * TT * DD;
    const u16* k1g = ws16 + 2 * TSZ + (size_t)bh * TT * DD;
    const u16* v0g = ws16 + 3 * TSZ + (size_t)bh * TT * DD;
    const u16* v1g = ws16 + 4 * TSZ + (size_t)bh * TT * DD;

    // ---- stage k1 (row-major, XOR swizzle: elem-col ^= (row&7)<<3) ----
#pragma unroll
    for (int it = 0; it < 6; it++) {
        const int flat = (it * 256 + tid) * 8;
        const int row = flat >> 6, c0 = flat & 63;
        uint4 b = *(const uint4*)(k1g + flat);
        *(uint4*)&k1L[row * DD + (c0 ^ ((row & 7) << 3))] = b;
    }

    // ---- stage v1^T (stride 200, conflict swz (pos>>3)^(d>>3)) with the
    //      K-slot permutation folded in: v1 row m -> pos bits {m3,m2,m4,m1,m0}
#pragma unroll
    for (int it = 0; it < 6; it++) {
        const int flat = (it * 256 + tid) * 8;
        const int row = flat >> 6, c0 = flat & 63;   // row=m, c0=d base
        uint4 b = *(const uint4*)(v1g + flat);
        u16 vb[8]; *(uint4*)vb = b;
        const int w5 = row & 31;
        const int pos = (row & ~31) | ((w5 & 12) << 1) | ((w5 >> 4) << 2) | (w5 & 3);
        const int swz = (((pos >> 3) ^ (c0 >> 3)) << 3) | (pos & 7);
#pragma unroll
        for (int j = 0; j < 8; j++)
            v1t[(c0 + j) * 200 + swz] = vb[j];
    }

    // ---- k-invariant k0 fragments (raw bf16, used to build afr per k) ----
    FragU k0f[3][2];
#pragma unroll
    for (int kk = 0; kk < 2; kk++)
#pragma unroll
        for (int rt = 0; rt < 3; rt++)
            k0f[rt][kk].u = *(const uint4*)(k0g + (size_t)(w * 48 + rt * 16 + li) * DD + kk * 32 + quad * 8);

    // ---- k-invariant v0 hoist: 48 bf16 packed 2/u32 -> 24 VGPRs ----
    u32 v0p[3][4][2];
#pragma unroll
    for (int rt = 0; rt < 3; rt++)
#pragma unroll
        for (int r = 0; r < 4; r++) {
            const int l = w * 48 + rt * 16 + quad * 4 + r;
            const u32 a0 = v0g[(size_t)l * DD + 0 * 16 + li];
            const u32 a1 = v0g[(size_t)l * DD + 1 * 16 + li];
            const u32 a2 = v0g[(size_t)l * DD + 2 * 16 + li];
            const u32 a3 = v0g[(size_t)l * DD + 3 * 16 + li];
            v0p[rt][r][0] = a0 | (a1 << 16);
            v0p[rt][r][1] = a2 | (a3 << 16);
        }

    FragU ones;
    ones.u = make_uint4(0x3F803F80u, 0x3F803F80u, 0x3F803F80u, 0x3F803F80u);

    __syncthreads();   // k1L + v1t staged

    // ======== sequential k loop (KG k's per block), BARRIER-FREE ========
#pragma unroll 1
    for (int kk6 = 0; kk6 < KG; kk6++) {
        const int k = kbase + kk6;

        // ---- afr: a[l,d] = bf16_trunc(scl*q[d]*k0[l,d]), scl=0.125*log2e ----
        FragU afr[3][2];
#pragma unroll
        for (int kk = 0; kk < 2; kk++) {
            uint4 qu = *(const uint4*)(qg0 + (size_t)k * DD + kk * 32 + quad * 8);
            u16 qv[8]; *(uint4*)qv = qu;
            float qf[8];
#pragma unroll
            for (int j = 0; j < 8; j++) qf[j] = bf2f(qv[j]) * 0.18033688f;
#pragma unroll
            for (int rt = 0; rt < 3; rt++) {
                u16 kv[8]; *(uint4*)kv = k0f[rt][kk].u;
                u32 pk[4];
#pragma unroll
                for (int p = 0; p < 4; p++) {
                    u32 lo = __float_as_uint(qf[2 * p] * bf2f(kv[2 * p]));
                    u32 hi = __float_as_uint(qf[2 * p + 1] * bf2f(kv[2 * p + 1]));
                    pk[p] = trunc_pk(hi, lo);
                }
                afr[rt][kk].u = make_uint4(pk[0], pk[1], pk[2], pk[3]);
            }
        }

        f32x4 Wacc[3][4], Zacc[3];
#pragma unroll
        for (int rt = 0; rt < 3; rt++) {
            Zacc[rt] = (f32x4){0.f, 0.f, 0.f, 0.f};
#pragma unroll
            for (int cd = 0; cd < 4; cd++) Wacc[rt][cd] = (f32x4){0.f, 0.f, 0.f, 0.f};
        }

        // ---- m-tile loop (6 x 32), barrier-free; kf from swizzled LDS ----
#pragma unroll
        for (int mt = 0; mt < 6; mt++) {
            FragU a2[3];
#pragma unroll
            for (int ct = 0; ct < 2; ct++) {
                const int r0 = mt * 32 + ct * 16 + li;
                const int sw = (r0 & 7) << 3;
                FragU kf0, kf1;
                kf0.u = *(const uint4*)&k1L[r0 * DD + ((quad * 8) ^ sw)];
                kf1.u = *(const uint4*)&k1L[r0 * DD + ((32 + quad * 8) ^ sw)];
#pragma unroll
                for (int rt = 0; rt < 3; rt++) {
                    f32x4 acc = (f32x4){0.f, 0.f, 0.f, 0.f};
                    acc = __builtin_amdgcn_mfma_f32_16x16x32_bf16(kf0.b, afr[rt][0].b, acc, 0, 0, 0);
                    acc = __builtin_amdgcn_mfma_f32_16x16x32_bf16(kf1.b, afr[rt][1].b, acc, 0, 0, 0);
                    const u32 lo = trunc_pk(__float_as_uint(EXP2F(acc[1])), __float_as_uint(EXP2F(acc[0])));
                    const u32 hi = trunc_pk(__float_as_uint(EXP2F(acc[3])), __float_as_uint(EXP2F(acc[2])));
                    if (ct == 0) { a2[rt].u.x = lo; a2[rt].u.y = hi; }
                    else         { a2[rt].u.z = lo; a2[rt].u.w = hi; }
                }
            }
            FragU b2[4];
#pragma unroll
            for (int cd = 0; cd < 4; cd++) {
                const int d = cd * 16 + li;
                b2[cd].u = *(const uint4*)&v1t[d * 200 + (((mt * 4 + quad) ^ (d >> 3)) << 3)];
            }
#pragma unroll
            for (int rt = 0; rt < 3; rt++) {
                Zacc[rt] = __builtin_amdgcn_mfma_f32_16x16x32_bf16(a2[rt].b, ones.b, Zacc[rt], 0, 0, 0);
#pragma unroll
                for (int cd = 0; cd < 4; cd++)
                    Wacc[rt][cd] = __builtin_amdgcn_mfma_f32_16x16x32_bf16(a2[rt].b, b2[cd].b, Wacc[rt][cd], 0, 0, 0);
            }
        }

        // ---- epilogue: v0 from hoisted regs (1 VALU unpack each) ----
        float op[4] = {0.f, 0.f, 0.f, 0.f};
#pragma unroll
        for (int rt = 0; rt < 3; rt++) {
#pragma unroll
            for (int r = 0; r < 4; r++) {
                const float iv = RCPF(Zacc[rt][r]);
                const float v00 = __uint_as_float(v0p[rt][r][0] << 16);
                const float v01 = __uint_as_float(v0p[rt][r][0] & 0xFFFF0000u);
                const float v02 = __uint_as_float(v0p[rt][r][1] << 16);
                const float v03 = __uint_as_float(v0p[rt][r][1] & 0xFFFF0000u);
                op[0] = fmaf(v00 * iv, Wacc[rt][0][r], op[0]);
                op[1] = fmaf(v01 * iv, Wacc[rt][1][r], op[1]);
                op[2] = fmaf(v02 * iv, Wacc[rt][2][r], op[2]);
                op[3] = fmaf(v03 * iv, Wacc[rt][3][r], op[3]);
            }
        }
#pragma unroll
        for (int cd = 0; cd < 4; cd++) {
            op[cd] += __shfl_xor(op[cd], 16);
            op[cd] += __shfl_xor(op[cd], 32);
        }
        if (quad == 0) {
#pragma unroll
            for (int cd = 0; cd < 4; cd++) osum[kk6][w][cd * 16 + li] = op[cd];
        }
    }

    __syncthreads();   // all (k,wave) osum slices written

    // ---- fused reduce + store: 256 threads = KG*64 outputs ----
    {
        const int kk6 = tid >> 6, d = tid & 63;
        const float o = osum[kk6][0][d] + osum[kk6][1][d] +
                        osum[kk6][2][d] + osum[kk6][3][d];
        const int b = bh >> 3, h = bh & 7;
        u16* ATT = ws16 + OFF_ATT;
        ATT[((size_t)(b * TT + kbase + kk6)) * CC + h * DD + d] = f2bf(o);
    }
}

extern "C" void kernel_launch(void* const* d_in, const int* in_sizes, int n_in,
                              void* d_out, int out_size, void* d_ws, size_t ws_size,
                              hipStream_t stream) {
    u16* ws16 = (u16*)d_ws;

    dim3 gp(CC / 64, MM / 64, 5);   // 8 x 6 x 5
    proj5_kernel<<<gp, 256, 0, stream>>>(
        d_in[0], d_in[1], d_in[2], d_in[3], d_in[4], d_in[5], d_in[6],
        d_in[7], d_in[8], d_in[9], d_in[10], ws16);

    dim3 ga(TT / KG, BB * HH);      // 48 x 16, four k per block = 3 blocks/CU
    attn_kernel<<<ga, 256, 0, stream>>>(ws16);

    dim3 go(CC / 64, MM / 64, 1);   // 8 x 6
    projo_kernel<<<go, 256, 0, stream>>>(ws16, d_in[11], d_in[12], d_out, d_in[0]);
}

// Round 8
// 153.864 us; speedup vs baseline: 1.0644x; 1.0644x over previous
//
#include <hip/hip_runtime.h>
#include <hip/hip_bf16.h>

typedef unsigned short u16;
typedef unsigned int u32;

#define TT 192
#define BB 2
#define HH 8
#define DD 64
#define CC 512
#define MM (BB*TT)   // 384
#define KG 4         // k-values per attention block (768 blocks = 3/CU exact)

// ws layout (u16 elements): Q,K0,K1,V0,V1 each [bh][t][d], then ATT [m][c]
#define TSZ   ((size_t)MM * CC)
#define OFF_ATT (5 * TSZ)

typedef short bf16x8 __attribute__((ext_vector_type(8)));
typedef float f32x4  __attribute__((ext_vector_type(4)));

union FragU { uint4 u; bf16x8 b; };

// Raw HW transcendentals (r13-verified: VALUBusy 58->27%)
#if __has_builtin(__builtin_amdgcn_exp2f)
#define EXP2F(x) __builtin_amdgcn_exp2f(x)
#else
#define EXP2F(x) exp2f(x)
#endif
#if __has_builtin(__builtin_amdgcn_rcpf)
#define RCPF(x) __builtin_amdgcn_rcpf(x)
#else
#define RCPF(x) (1.f / (x))
#endif

__device__ __forceinline__ float bf2f(u16 u) {
    return __uint_as_float(((u32)u) << 16);
}
__device__ __forceinline__ u16 f2bf(float f) {
    u32 u = __float_as_uint(f);
    u32 r = u + 0x7FFFu + ((u >> 16) & 1u);   // RNE
    return (u16)(r >> 16);
}
// pack hi16(a),hi16(b) -> one u32 (truncation round; bias cancels in P/Z)
__device__ __forceinline__ u32 trunc_pk(u32 b_hi, u32 a_lo) {
    return __builtin_amdgcn_perm(b_hi, a_lo, 0x07060302u);
}

// dtype detect: 1 load + ballot. bf16 data => low u16 exponent near 127.
__device__ __forceinline__ u32 detect_bf16_fast(const u32* __restrict__ x) {
    const int lane = threadIdx.x & 63;
    u32 v = x[lane & 31];
    u32 e = (v >> 7) & 0xFF;
    unsigned long long m = __ballot(e >= 113 && e <= 133);
    return (__popcll(m) >= 32) ? 1u : 0u;
}

// dtype-aware 16-element load (two uint4 of packed bf16)
__device__ __forceinline__ void ld16(const void* __restrict__ base, size_t off, u32 fl,
                                     uint4& lo, uint4& hi) {
    if (fl) {
        const uint4* p = (const uint4*)((const u16*)base + off);
        lo = p[0]; hi = p[1];
    } else {
        const float* s = (const float*)base + off;
        float4 f0 = *(const float4*)(s);
        float4 f1 = *(const float4*)(s + 4);
        float4 f2 = *(const float4*)(s + 8);
        float4 f3 = *(const float4*)(s + 12);
        lo = make_uint4((u32)f2bf(f0.x) | ((u32)f2bf(f0.y) << 16),
                        (u32)f2bf(f0.z) | ((u32)f2bf(f0.w) << 16),
                        (u32)f2bf(f1.x) | ((u32)f2bf(f1.y) << 16),
                        (u32)f2bf(f1.z) | ((u32)f2bf(f1.w) << 16));
        hi = make_uint4((u32)f2bf(f2.x) | ((u32)f2bf(f2.y) << 16),
                        (u32)f2bf(f2.z) | ((u32)f2bf(f2.w) << 16),
                        (u32)f2bf(f3.x) | ((u32)f2bf(f3.y) << 16),
                        (u32)f2bf(f3.z) | ((u32)f2bf(f3.w) << 16));
    }
}

// ---------------------------------------------------------------------------
// LDS-staged MFMA projection GEMM (r9-verified): out = A @ W^T + bias.
// ---------------------------------------------------------------------------
__device__ __forceinline__ void proj_lds(const void* __restrict__ A, u32 aFl,
                                         const void* __restrict__ W,
                                         const void* __restrict__ bias, u32 wFl,
                                         void* __restrict__ out, int headperm, u32 outFl) {
    __shared__ __align__(16) u16 As[64][72];
    __shared__ __align__(16) u16 Ws[64][72];
    const int tid = threadIdx.x;
    const int w = tid >> 6, lane = tid & 63;
    const int quad = lane >> 4, li = lane & 15;
    const int mb = blockIdx.y * 64, nb = blockIdx.x * 64;

    const int r = tid >> 2;
    const int c = (tid & 3) * 16;

    const size_t abase = (size_t)(mb + r) * CC + c;
    const size_t wbase = (size_t)(nb + r) * CC + c;

    f32x4 acc[4];
#pragma unroll
    for (int ct = 0; ct < 4; ct++) acc[ct] = (f32x4){0.f, 0.f, 0.f, 0.f};

    uint4 a0, a1, w0, w1;
    ld16(A, abase, aFl, a0, a1);
    ld16(W, wbase, wFl, w0, w1);

#pragma unroll
    for (int step = 0; step < 8; step++) {
        *(uint4*)&As[r][c] = a0; *(uint4*)&As[r][c + 8] = a1;
        *(uint4*)&Ws[r][c] = w0; *(uint4*)&Ws[r][c + 8] = w1;
        __syncthreads();
        if (step < 7) {
            const int kb = (step + 1) * 64;
            ld16(A, abase + kb, aFl, a0, a1);
            ld16(W, wbase + kb, wFl, w0, w1);
        }
#pragma unroll
        for (int kk = 0; kk < 2; kk++) {
            FragU af; af.u = *(const uint4*)&As[w * 16 + li][kk * 32 + quad * 8];
#pragma unroll
            for (int ct = 0; ct < 4; ct++) {
                FragU wf; wf.u = *(const uint4*)&Ws[ct * 16 + li][kk * 32 + quad * 8];
                acc[ct] = __builtin_amdgcn_mfma_f32_16x16x32_bf16(af.b, wf.b, acc[ct], 0, 0, 0);
            }
        }
        __syncthreads();
    }

#pragma unroll
    for (int ct = 0; ct < 4; ct++) {
        const int n = nb + ct * 16 + li;
        const float bv = wFl ? bf2f(((const u16*)bias)[n]) : ((const float*)bias)[n];
#pragma unroll
        for (int rr = 0; rr < 4; rr++) {
            const int m = mb + w * 16 + quad * 4 + rr;
            const float v = acc[ct][rr] + bv;
            if (headperm) {
                const int b = (m >= TT) ? 1 : 0;
                const int tloc = m - b * TT;
                ((u16*)out)[((size_t)(b * HH + (n >> 6)) * TT + tloc) * DD + (n & 63)] = f2bf(v);
            } else {
                if (outFl) ((u16*)out)[(size_t)m * CC + n] = f2bf(v);
                else       ((float*)out)[(size_t)m * CC + n] = v;
            }
        }
    }
}

__global__ __launch_bounds__(256) void proj5_kernel(
    const void* __restrict__ x,
    const void* __restrict__ Wq,  const void* __restrict__ bq,
    const void* __restrict__ Wk0, const void* __restrict__ bk0,
    const void* __restrict__ Wk1, const void* __restrict__ bk1,
    const void* __restrict__ Wv0, const void* __restrict__ bv0,
    const void* __restrict__ Wv1, const void* __restrict__ bv1,
    u16* __restrict__ ws16) {
    const u32 fl = detect_bf16_fast((const u32*)x);
    const int z = blockIdx.z;
    const void* W; const void* bi;
    switch (z) {
        case 0:  W = Wq;  bi = bq;  break;
        case 1:  W = Wk0; bi = bk0; break;
        case 2:  W = Wk1; bi = bk1; break;
        case 3:  W = Wv0; bi = bv0; break;
        default: W = Wv1; bi = bv1; break;
    }
    proj_lds(x, fl, W, bi, fl, (void*)(ws16 + (size_t)z * TSZ), 1, 1u);
}

__global__ __launch_bounds__(256) void projo_kernel(const u16* __restrict__ ws16,
                                                    const void* __restrict__ Wo,
                                                    const void* __restrict__ bo,
                                                    void* __restrict__ out,
                                                    const void* __restrict__ xorig) {
    const u32 fl = detect_bf16_fast((const u32*)xorig);
    proj_lds(ws16 + OFF_ATT, 1u, Wo, bo, fl, out, 0, fl);
}

// ---------------------------------------------------------------------------
// MFMA attention, r21: r18 base + v0 hoist ONLY (r20 decomposition).
// r20 post-mortem: barrier-free k-loop + v0 hoist together -> VGPR 212,
// occupancy 9.5%, 67us. The per-k barrier is a live-range fence the
// compiler needs; removing it (not the 24-reg v0p) caused the blowup.
// So: r18 structure byte-identical (KG=4, 3 blocks/CU, LDS-resident
// swizzled k1, amortized v1t, register-resident P, per-k osum barrier),
// ONE change: v0 (k-invariant) loaded once per block during staging,
// packed 2/u32 into 24 VGPRs; per-k epilogue unpacks with 1 VALU op each.
// Removes 144 of 192 per-wave global loads from the k-loop serial chain.
// Register window lesson (r15/r20): target VGPR 145-160; >170 = revert.
// LDS: k1L 24576 + v1t 25600 + osum 2048 = 52224 B -> 3 blocks/CU.
// ---------------------------------------------------------------------------
__global__ __launch_bounds__(256) void attn_kernel(u16* __restrict__ ws16) {
    __shared__ __align__(16) u16 k1L[TT * DD];      // 24576 B, XOR-swizzled
    __shared__ __align__(16) u16 v1t[DD * 200];     // 25600 B, r14 layout
    __shared__ float osum[2][256];                  // 2048 B, parity dbuf
    const int tid = threadIdx.x;
    const int w = tid >> 6, lane = tid & 63;
    const int quad = lane >> 4, li = lane & 15;
    const int kbase = blockIdx.x * KG, bh = blockIdx.y;

    const u16* qg0 = ws16 + ((size_t)bh * TT) * DD;
    const u16* k0g = ws16 + TSZ     + (size_t)bh * TT * DD;
    const u16* k1g = ws16 + 2 * TSZ + (size_t)bh * TT * DD;
    const u16* v0g = ws16 + 3 * TSZ + (size_t)bh * TT * DD;
    const u16* v1g = ws16 + 4 * TSZ + (size_t)bh * TT * DD;

    // ---- stage k1 (row-major, XOR swizzle: elem-col ^= (row&7)<<3) ----
#pragma unroll
    for (int it = 0; it < 6; it++) {
        const int flat = (it * 256 + tid) * 8;
        const int row = flat >> 6, c0 = flat & 63;
        uint4 b = *(const uint4*)(k1g + flat);
        *(uint4*)&k1L[row * DD + (c0 ^ ((row & 7) << 3))] = b;
    }

    // ---- stage v1^T (stride 200, conflict swz (pos>>3)^(d>>3)) with the
    //      K-slot permutation folded in: v1 row m -> pos bits {m3,m2,m4,m1,m0}
#pragma unroll
    for (int it = 0; it < 6; it++) {
        const int flat = (it * 256 + tid) * 8;
        const int row = flat >> 6, c0 = flat & 63;   // row=m, c0=d base
        uint4 b = *(const uint4*)(v1g + flat);
        u16 vb[8]; *(uint4*)vb = b;
        const int w5 = row & 31;
        const int pos = (row & ~31) | ((w5 & 12) << 1) | ((w5 >> 4) << 2) | (w5 & 3);
        const int swz = (((pos >> 3) ^ (c0 >> 3)) << 3) | (pos & 7);
#pragma unroll
        for (int j = 0; j < 8; j++)
            v1t[(c0 + j) * 200 + swz] = vb[j];
    }

    // ---- k-invariant k0 fragments (raw bf16, used to build afr per k) ----
    FragU k0f[3][2];
#pragma unroll
    for (int kk = 0; kk < 2; kk++)
#pragma unroll
        for (int rt = 0; rt < 3; rt++)
            k0f[rt][kk].u = *(const uint4*)(k0g + (size_t)(w * 48 + rt * 16 + li) * DD + kk * 32 + quad * 8);

    // ---- k-invariant v0 hoist: 48 bf16 packed 2/u32 -> 24 VGPRs ----
    u32 v0p[3][4][2];
#pragma unroll
    for (int rt = 0; rt < 3; rt++)
#pragma unroll
        for (int r = 0; r < 4; r++) {
            const int l = w * 48 + rt * 16 + quad * 4 + r;
            const u32 a0 = v0g[(size_t)l * DD + 0 * 16 + li];
            const u32 a1 = v0g[(size_t)l * DD + 1 * 16 + li];
            const u32 a2 = v0g[(size_t)l * DD + 2 * 16 + li];
            const u32 a3 = v0g[(size_t)l * DD + 3 * 16 + li];
            v0p[rt][r][0] = a0 | (a1 << 16);
            v0p[rt][r][1] = a2 | (a3 << 16);
        }

    FragU ones;
    ones.u = make_uint4(0x3F803F80u, 0x3F803F80u, 0x3F803F80u, 0x3F803F80u);

    __syncthreads();   // k1L + v1t staged

    // ================= sequential k loop (KG k's per block) =================
#pragma unroll 1
    for (int kk6 = 0; kk6 < KG; kk6++) {
        const int k = kbase + kk6;

        // ---- afr: a[l,d] = bf16_trunc(scl*q[d]*k0[l,d]), scl=0.125*log2e ----
        FragU afr[3][2];
#pragma unroll
        for (int kk = 0; kk < 2; kk++) {
            uint4 qu = *(const uint4*)(qg0 + (size_t)k * DD + kk * 32 + quad * 8);
            u16 qv[8]; *(uint4*)qv = qu;
            float qf[8];
#pragma unroll
            for (int j = 0; j < 8; j++) qf[j] = bf2f(qv[j]) * 0.18033688f;
#pragma unroll
            for (int rt = 0; rt < 3; rt++) {
                u16 kv[8]; *(uint4*)kv = k0f[rt][kk].u;
                u32 pk[4];
#pragma unroll
                for (int p = 0; p < 4; p++) {
                    u32 lo = __float_as_uint(qf[2 * p] * bf2f(kv[2 * p]));
                    u32 hi = __float_as_uint(qf[2 * p + 1] * bf2f(kv[2 * p + 1]));
                    pk[p] = trunc_pk(hi, lo);
                }
                afr[rt][kk].u = make_uint4(pk[0], pk[1], pk[2], pk[3]);
            }
        }

        f32x4 Wacc[3][4], Zacc[3];
#pragma unroll
        for (int rt = 0; rt < 3; rt++) {
            Zacc[rt] = (f32x4){0.f, 0.f, 0.f, 0.f};
#pragma unroll
            for (int cd = 0; cd < 4; cd++) Wacc[rt][cd] = (f32x4){0.f, 0.f, 0.f, 0.f};
        }

        // ---- m-tile loop (6 x 32), barrier-free; kf from swizzled LDS ----
#pragma unroll
        for (int mt = 0; mt < 6; mt++) {
            FragU a2[3];
#pragma unroll
            for (int ct = 0; ct < 2; ct++) {
                const int r0 = mt * 32 + ct * 16 + li;
                const int sw = (r0 & 7) << 3;
                FragU kf0, kf1;
                kf0.u = *(const uint4*)&k1L[r0 * DD + ((quad * 8) ^ sw)];
                kf1.u = *(const uint4*)&k1L[r0 * DD + ((32 + quad * 8) ^ sw)];
#pragma unroll
                for (int rt = 0; rt < 3; rt++) {
                    f32x4 acc = (f32x4){0.f, 0.f, 0.f, 0.f};
                    acc = __builtin_amdgcn_mfma_f32_16x16x32_bf16(kf0.b, afr[rt][0].b, acc, 0, 0, 0);
                    acc = __builtin_amdgcn_mfma_f32_16x16x32_bf16(kf1.b, afr[rt][1].b, acc, 0, 0, 0);
                    const u32 lo = trunc_pk(__float_as_uint(EXP2F(acc[1])), __float_as_uint(EXP2F(acc[0])));
                    const u32 hi = trunc_pk(__float_as_uint(EXP2F(acc[3])), __float_as_uint(EXP2F(acc[2])));
                    if (ct == 0) { a2[rt].u.x = lo; a2[rt].u.y = hi; }
                    else         { a2[rt].u.z = lo; a2[rt].u.w = hi; }
                }
            }
            FragU b2[4];
#pragma unroll
            for (int cd = 0; cd < 4; cd++) {
                const int d = cd * 16 + li;
                b2[cd].u = *(const uint4*)&v1t[d * 200 + (((mt * 4 + quad) ^ (d >> 3)) << 3)];
            }
#pragma unroll
            for (int rt = 0; rt < 3; rt++) {
                Zacc[rt] = __builtin_amdgcn_mfma_f32_16x16x32_bf16(a2[rt].b, ones.b, Zacc[rt], 0, 0, 0);
#pragma unroll
                for (int cd = 0; cd < 4; cd++)
                    Wacc[rt][cd] = __builtin_amdgcn_mfma_f32_16x16x32_bf16(a2[rt].b, b2[cd].b, Wacc[rt][cd], 0, 0, 0);
            }
        }

        // ---- epilogue: v0 from hoisted regs (1 VALU unpack each) ----
        float op[4] = {0.f, 0.f, 0.f, 0.f};
#pragma unroll
        for (int rt = 0; rt < 3; rt++) {
#pragma unroll
            for (int r = 0; r < 4; r++) {
                const float iv = RCPF(Zacc[rt][r]);
                const float v00 = __uint_as_float(v0p[rt][r][0] << 16);
                const float v01 = __uint_as_float(v0p[rt][r][0] & 0xFFFF0000u);
                const float v02 = __uint_as_float(v0p[rt][r][1] << 16);
                const float v03 = __uint_as_float(v0p[rt][r][1] & 0xFFFF0000u);
                op[0] = fmaf(v00 * iv, Wacc[rt][0][r], op[0]);
                op[1] = fmaf(v01 * iv, Wacc[rt][1][r], op[1]);
                op[2] = fmaf(v02 * iv, Wacc[rt][2][r], op[2]);
                op[3] = fmaf(v03 * iv, Wacc[rt][3][r], op[3]);
            }
        }
#pragma unroll
        for (int cd = 0; cd < 4; cd++) {
            op[cd] += __shfl_xor(op[cd], 16);
            op[cd] += __shfl_xor(op[cd], 32);
        }
        float* os = osum[kk6 & 1];
        if (quad == 0) {
#pragma unroll
            for (int cd = 0; cd < 4; cd++) os[w * 64 + cd * 16 + li] = op[cd];
        }
        __syncthreads();
        if (tid < DD) {
            const float o = os[tid] + os[64 + tid] + os[128 + tid] + os[192 + tid];
            const int b = bh >> 3, h = bh & 7;
            u16* ATT = ws16 + OFF_ATT;
            ATT[((size_t)(b * TT + k)) * CC + h * DD + tid] = f2bf(o);
        }
    }
}

extern "C" void kernel_launch(void* const* d_in, const int* in_sizes, int n_in,
                              void* d_out, int out_size, void* d_ws, size_t ws_size,
                              hipStream_t stream) {
    u16* ws16 = (u16*)d_ws;

    dim3 gp(CC / 64, MM / 64, 5);   // 8 x 6 x 5
    proj5_kernel<<<gp, 256, 0, stream>>>(
        d_in[0], d_in[1], d_in[2], d_in[3], d_in[4], d_in[5], d_in[6],
        d_in[7], d_in[8], d_in[9], d_in[10], ws16);

    dim3 ga(TT / KG, BB * HH);      // 48 x 16, four k per block = 3 blocks/CU
    attn_kernel<<<ga, 256, 0, stream>>>(ws16);

    dim3 go(CC / 64, MM / 64, 1);   // 8 x 6
    projo_kernel<<<go, 256, 0, stream>>>(ws16, d_in[11], d_in[12], d_out, d_in[0]);
}

// Round 9
// 150.781 us; speedup vs baseline: 1.0862x; 1.0205x over previous
//
#include <hip/hip_runtime.h>
#include <hip/hip_bf16.h>

typedef unsigned short u16;
typedef unsigned int u32;

#define TT 192
#define BB 2
#define HH 8
#define DD 64
#define CC 512
#define MM (BB*TT)   // 384
#define KG 4         // k-values per attention block (768 blocks = 3/CU exact)

// ws layout (u16 elements): Q,K0,K1,V0,V1 each [bh][t][d], then ATT [m][c]
#define TSZ   ((size_t)MM * CC)
#define OFF_ATT (5 * TSZ)

typedef short bf16x8 __attribute__((ext_vector_type(8)));
typedef float f32x4  __attribute__((ext_vector_type(4)));

union FragU { uint4 u; bf16x8 b; };

// Raw HW transcendentals (r13-verified: VALUBusy 58->27%)
#if __has_builtin(__builtin_amdgcn_exp2f)
#define EXP2F(x) __builtin_amdgcn_exp2f(x)
#else
#define EXP2F(x) exp2f(x)
#endif
#if __has_builtin(__builtin_amdgcn_rcpf)
#define RCPF(x) __builtin_amdgcn_rcpf(x)
#else
#define RCPF(x) (1.f / (x))
#endif

__device__ __forceinline__ float bf2f(u16 u) {
    return __uint_as_float(((u32)u) << 16);
}
__device__ __forceinline__ u16 f2bf(float f) {
    u32 u = __float_as_uint(f);
    u32 r = u + 0x7FFFu + ((u >> 16) & 1u);   // RNE
    return (u16)(r >> 16);
}
// pack hi16(a),hi16(b) -> one u32 (truncation round; bias cancels in P/Z)
__device__ __forceinline__ u32 trunc_pk(u32 b_hi, u32 a_lo) {
    return __builtin_amdgcn_perm(b_hi, a_lo, 0x07060302u);
}

// dtype detect: 1 load + ballot. bf16 data => low u16 exponent near 127.
__device__ __forceinline__ u32 detect_bf16_fast(const u32* __restrict__ x) {
    const int lane = threadIdx.x & 63;
    u32 v = x[lane & 31];
    u32 e = (v >> 7) & 0xFF;
    unsigned long long m = __ballot(e >= 113 && e <= 133);
    return (__popcll(m) >= 32) ? 1u : 0u;
}

// dtype-aware 16-element load (two uint4 of packed bf16)
__device__ __forceinline__ void ld16(const void* __restrict__ base, size_t off, u32 fl,
                                     uint4& lo, uint4& hi) {
    if (fl) {
        const uint4* p = (const uint4*)((const u16*)base + off);
        lo = p[0]; hi = p[1];
    } else {
        const float* s = (const float*)base + off;
        float4 f0 = *(const float4*)(s);
        float4 f1 = *(const float4*)(s + 4);
        float4 f2 = *(const float4*)(s + 8);
        float4 f3 = *(const float4*)(s + 12);
        lo = make_uint4((u32)f2bf(f0.x) | ((u32)f2bf(f0.y) << 16),
                        (u32)f2bf(f0.z) | ((u32)f2bf(f0.w) << 16),
                        (u32)f2bf(f1.x) | ((u32)f2bf(f1.y) << 16),
                        (u32)f2bf(f1.z) | ((u32)f2bf(f1.w) << 16));
        hi = make_uint4((u32)f2bf(f2.x) | ((u32)f2bf(f2.y) << 16),
                        (u32)f2bf(f2.z) | ((u32)f2bf(f2.w) << 16),
                        (u32)f2bf(f3.x) | ((u32)f2bf(f3.y) << 16),
                        (u32)f2bf(f3.z) | ((u32)f2bf(f3.w) << 16));
    }
}

// ---------------------------------------------------------------------------
// LDS-staged MFMA projection GEMM (r9-verified): out = A @ W^T + bias.
// ---------------------------------------------------------------------------
__device__ __forceinline__ void proj_lds(const void* __restrict__ A, u32 aFl,
                                         const void* __restrict__ W,
                                         const void* __restrict__ bias, u32 wFl,
                                         void* __restrict__ out, int headperm, u32 outFl) {
    __shared__ __align__(16) u16 As[64][72];
    __shared__ __align__(16) u16 Ws[64][72];
    const int tid = threadIdx.x;
    const int w = tid >> 6, lane = tid & 63;
    const int quad = lane >> 4, li = lane & 15;
    const int mb = blockIdx.y * 64, nb = blockIdx.x * 64;

    const int r = tid >> 2;
    const int c = (tid & 3) * 16;

    const size_t abase = (size_t)(mb + r) * CC + c;
    const size_t wbase = (size_t)(nb + r) * CC + c;

    f32x4 acc[4];
#pragma unroll
    for (int ct = 0; ct < 4; ct++) acc[ct] = (f32x4){0.f, 0.f, 0.f, 0.f};

    uint4 a0, a1, w0, w1;
    ld16(A, abase, aFl, a0, a1);
    ld16(W, wbase, wFl, w0, w1);

#pragma unroll
    for (int step = 0; step < 8; step++) {
        *(uint4*)&As[r][c] = a0; *(uint4*)&As[r][c + 8] = a1;
        *(uint4*)&Ws[r][c] = w0; *(uint4*)&Ws[r][c + 8] = w1;
        __syncthreads();
        if (step < 7) {
            const int kb = (step + 1) * 64;
            ld16(A, abase + kb, aFl, a0, a1);
            ld16(W, wbase + kb, wFl, w0, w1);
        }
#pragma unroll
        for (int kk = 0; kk < 2; kk++) {
            FragU af; af.u = *(const uint4*)&As[w * 16 + li][kk * 32 + quad * 8];
#pragma unroll
            for (int ct = 0; ct < 4; ct++) {
                FragU wf; wf.u = *(const uint4*)&Ws[ct * 16 + li][kk * 32 + quad * 8];
                acc[ct] = __builtin_amdgcn_mfma_f32_16x16x32_bf16(af.b, wf.b, acc[ct], 0, 0, 0);
            }
        }
        __syncthreads();
    }

#pragma unroll
    for (int ct = 0; ct < 4; ct++) {
        const int n = nb + ct * 16 + li;
        const float bv = wFl ? bf2f(((const u16*)bias)[n]) : ((const float*)bias)[n];
#pragma unroll
        for (int rr = 0; rr < 4; rr++) {
            const int m = mb + w * 16 + quad * 4 + rr;
            const float v = acc[ct][rr] + bv;
            if (headperm) {
                const int b = (m >= TT) ? 1 : 0;
                const int tloc = m - b * TT;
                ((u16*)out)[((size_t)(b * HH + (n >> 6)) * TT + tloc) * DD + (n & 63)] = f2bf(v);
            } else {
                if (outFl) ((u16*)out)[(size_t)m * CC + n] = f2bf(v);
                else       ((float*)out)[(size_t)m * CC + n] = v;
            }
        }
    }
}

__global__ __launch_bounds__(256) void proj5_kernel(
    const void* __restrict__ x,
    const void* __restrict__ Wq,  const void* __restrict__ bq,
    const void* __restrict__ Wk0, const void* __restrict__ bk0,
    const void* __restrict__ Wk1, const void* __restrict__ bk1,
    const void* __restrict__ Wv0, const void* __restrict__ bv0,
    const void* __restrict__ Wv1, const void* __restrict__ bv1,
    u16* __restrict__ ws16) {
    const u32 fl = detect_bf16_fast((const u32*)x);
    const int z = blockIdx.z;
    const void* W; const void* bi;
    switch (z) {
        case 0:  W = Wq;  bi = bq;  break;
        case 1:  W = Wk0; bi = bk0; break;
        case 2:  W = Wk1; bi = bk1; break;
        case 3:  W = Wv0; bi = bv0; break;
        default: W = Wv1; bi = bv1; break;
    }
    proj_lds(x, fl, W, bi, fl, (void*)(ws16 + (size_t)z * TSZ), 1, 1u);
}

__global__ __launch_bounds__(256) void projo_kernel(const u16* __restrict__ ws16,
                                                    const void* __restrict__ Wo,
                                                    const void* __restrict__ bo,
                                                    void* __restrict__ out,
                                                    const void* __restrict__ xorig) {
    const u32 fl = detect_bf16_fast((const u32*)xorig);
    proj_lds(ws16 + OFF_ATT, 1u, Wo, bo, fl, out, 0, fl);
}

// ---------------------------------------------------------------------------
// MFMA attention, r22: 6-wave x 2-rt geometry (r18 otherwise unchanged).
// r21 post-mortem: residency is on a register cliff at ~124 VGPR; any state
// growth evicts a block (occ 15.7->10, dur 44->57.5). r19's failure was
// lockstep+exchange, r15's was the forced VGPR cap. This round shrinks BOTH
// per-wave state and per-wave chain WITHOUT caps or lockstep:
//  - 384 threads, 6 waves; wave w owns l in [32w, 32w+32) (rt<2).
//  - Per-wave per-k: 108 MFMA + 96 exp (was 162/144); Wacc 32, Zacc 8,
//    afr 16, k0f 16 regs -> est. VGPR 90-105 (-30 vs r18).
//  - Each wave still covers full m for its l-rows -> NO Z exchange, NO
//    lockstep; per-k osum barrier kept (live-range fence, r20 lesson).
//  - KG=4: grid 48x16 = 768 blocks; LDS 53248 B -> 3 blocks/CU; if VGPR
//    <=102 that is 18 resident waves/CU with 2/3-length chains.
// k1L swizzled-LDS, v1t scatter + m-permutation (register-resident P),
// per-k v0 epilogue loads: all r18-identical.
// LDS: k1L 24576 + v1t 25600 + osum 3072 = 53248 B.
// ---------------------------------------------------------------------------
__global__ __launch_bounds__(384) void attn_kernel(u16* __restrict__ ws16) {
    __shared__ __align__(16) u16 k1L[TT * DD];      // 24576 B, XOR-swizzled
    __shared__ __align__(16) u16 v1t[DD * 200];     // 25600 B, r14 layout
    __shared__ float osum[2][384];                  // 3072 B, parity dbuf
    const int tid = threadIdx.x;
    const int w = tid >> 6, lane = tid & 63;
    const int quad = lane >> 4, li = lane & 15;
    const int kbase = blockIdx.x * KG, bh = blockIdx.y;

    const u16* qg0 = ws16 + ((size_t)bh * TT) * DD;
    const u16* k0g = ws16 + TSZ     + (size_t)bh * TT * DD;
    const u16* k1g = ws16 + 2 * TSZ + (size_t)bh * TT * DD;
    const u16* v0g = ws16 + 3 * TSZ + (size_t)bh * TT * DD;
    const u16* v1g = ws16 + 4 * TSZ + (size_t)bh * TT * DD;

    // ---- stage k1 (row-major, XOR swizzle: elem-col ^= (row&7)<<3) ----
#pragma unroll
    for (int it = 0; it < 4; it++) {
        const int flat = (it * 384 + tid) * 8;
        const int row = flat >> 6, c0 = flat & 63;
        uint4 b = *(const uint4*)(k1g + flat);
        *(uint4*)&k1L[row * DD + (c0 ^ ((row & 7) << 3))] = b;
    }

    // ---- stage v1^T (stride 200, conflict swz (pos>>3)^(d>>3)) with the
    //      K-slot permutation folded in: v1 row m -> pos bits {m3,m2,m4,m1,m0}
#pragma unroll
    for (int it = 0; it < 4; it++) {
        const int flat = (it * 384 + tid) * 8;
        const int row = flat >> 6, c0 = flat & 63;   // row=m, c0=d base
        uint4 b = *(const uint4*)(v1g + flat);
        u16 vb[8]; *(uint4*)vb = b;
        const int w5 = row & 31;
        const int pos = (row & ~31) | ((w5 & 12) << 1) | ((w5 >> 4) << 2) | (w5 & 3);
        const int swz = (((pos >> 3) ^ (c0 >> 3)) << 3) | (pos & 7);
#pragma unroll
        for (int j = 0; j < 8; j++)
            v1t[(c0 + j) * 200 + swz] = vb[j];
    }

    // ---- k-invariant k0 fragments (raw bf16, used to build afr per k) ----
    FragU k0f[2][2];
#pragma unroll
    for (int kk = 0; kk < 2; kk++)
#pragma unroll
        for (int rt = 0; rt < 2; rt++)
            k0f[rt][kk].u = *(const uint4*)(k0g + (size_t)(w * 32 + rt * 16 + li) * DD + kk * 32 + quad * 8);

    FragU ones;
    ones.u = make_uint4(0x3F803F80u, 0x3F803F80u, 0x3F803F80u, 0x3F803F80u);

    __syncthreads();   // k1L + v1t staged

    // ================= sequential k loop (KG k's per block) =================
#pragma unroll 1
    for (int kk6 = 0; kk6 < KG; kk6++) {
        const int k = kbase + kk6;

        // ---- afr: a[l,d] = bf16_trunc(scl*q[d]*k0[l,d]), scl=0.125*log2e ----
        FragU afr[2][2];
#pragma unroll
        for (int kk = 0; kk < 2; kk++) {
            uint4 qu = *(const uint4*)(qg0 + (size_t)k * DD + kk * 32 + quad * 8);
            u16 qv[8]; *(uint4*)qv = qu;
            float qf[8];
#pragma unroll
            for (int j = 0; j < 8; j++) qf[j] = bf2f(qv[j]) * 0.18033688f;
#pragma unroll
            for (int rt = 0; rt < 2; rt++) {
                u16 kv[8]; *(uint4*)kv = k0f[rt][kk].u;
                u32 pk[4];
#pragma unroll
                for (int p = 0; p < 4; p++) {
                    u32 lo = __float_as_uint(qf[2 * p] * bf2f(kv[2 * p]));
                    u32 hi = __float_as_uint(qf[2 * p + 1] * bf2f(kv[2 * p + 1]));
                    pk[p] = trunc_pk(hi, lo);
                }
                afr[rt][kk].u = make_uint4(pk[0], pk[1], pk[2], pk[3]);
            }
        }

        f32x4 Wacc[2][4], Zacc[2];
#pragma unroll
        for (int rt = 0; rt < 2; rt++) {
            Zacc[rt] = (f32x4){0.f, 0.f, 0.f, 0.f};
#pragma unroll
            for (int cd = 0; cd < 4; cd++) Wacc[rt][cd] = (f32x4){0.f, 0.f, 0.f, 0.f};
        }

        // ---- m-tile loop (6 x 32), barrier-free; kf from swizzled LDS ----
#pragma unroll
        for (int mt = 0; mt < 6; mt++) {
            FragU a2[2];
#pragma unroll
            for (int ct = 0; ct < 2; ct++) {
                const int r0 = mt * 32 + ct * 16 + li;
                const int sw = (r0 & 7) << 3;
                FragU kf0, kf1;
                kf0.u = *(const uint4*)&k1L[r0 * DD + ((quad * 8) ^ sw)];
                kf1.u = *(const uint4*)&k1L[r0 * DD + ((32 + quad * 8) ^ sw)];
#pragma unroll
                for (int rt = 0; rt < 2; rt++) {
                    f32x4 acc = (f32x4){0.f, 0.f, 0.f, 0.f};
                    acc = __builtin_amdgcn_mfma_f32_16x16x32_bf16(kf0.b, afr[rt][0].b, acc, 0, 0, 0);
                    acc = __builtin_amdgcn_mfma_f32_16x16x32_bf16(kf1.b, afr[rt][1].b, acc, 0, 0, 0);
                    const u32 lo = trunc_pk(__float_as_uint(EXP2F(acc[1])), __float_as_uint(EXP2F(acc[0])));
                    const u32 hi = trunc_pk(__float_as_uint(EXP2F(acc[3])), __float_as_uint(EXP2F(acc[2])));
                    if (ct == 0) { a2[rt].u.x = lo; a2[rt].u.y = hi; }
                    else         { a2[rt].u.z = lo; a2[rt].u.w = hi; }
                }
            }
            FragU b2[4];
#pragma unroll
            for (int cd = 0; cd < 4; cd++) {
                const int d = cd * 16 + li;
                b2[cd].u = *(const uint4*)&v1t[d * 200 + (((mt * 4 + quad) ^ (d >> 3)) << 3)];
            }
#pragma unroll
            for (int rt = 0; rt < 2; rt++) {
                Zacc[rt] = __builtin_amdgcn_mfma_f32_16x16x32_bf16(a2[rt].b, ones.b, Zacc[rt], 0, 0, 0);
#pragma unroll
                for (int cd = 0; cd < 4; cd++)
                    Wacc[rt][cd] = __builtin_amdgcn_mfma_f32_16x16x32_bf16(a2[rt].b, b2[cd].b, Wacc[rt][cd], 0, 0, 0);
            }
        }

        // ---- epilogue: v0 from global (L2-hot), per-rt to cap live VGPRs ----
        float op[4] = {0.f, 0.f, 0.f, 0.f};
#pragma unroll
        for (int rt = 0; rt < 2; rt++) {
            float v0v[4][4];
#pragma unroll
            for (int r = 0; r < 4; r++) {
                const int l = w * 32 + rt * 16 + quad * 4 + r;
#pragma unroll
                for (int cd = 0; cd < 4; cd++)
                    v0v[r][cd] = bf2f(v0g[(size_t)l * DD + cd * 16 + li]);
            }
#pragma unroll
            for (int r = 0; r < 4; r++) {
                const float iv = RCPF(Zacc[rt][r]);
#pragma unroll
                for (int cd = 0; cd < 4; cd++)
                    op[cd] = fmaf(v0v[r][cd] * iv, Wacc[rt][cd][r], op[cd]);
            }
        }
#pragma unroll
        for (int cd = 0; cd < 4; cd++) {
            op[cd] += __shfl_xor(op[cd], 16);
            op[cd] += __shfl_xor(op[cd], 32);
        }
        float* os = osum[kk6 & 1];
        if (quad == 0) {
#pragma unroll
            for (int cd = 0; cd < 4; cd++) os[w * 64 + cd * 16 + li] = op[cd];
        }
        __syncthreads();
        if (tid < DD) {
            const float o = os[tid] + os[64 + tid] + os[128 + tid] +
                            os[192 + tid] + os[256 + tid] + os[320 + tid];
            const int b = bh >> 3, h = bh & 7;
            u16* ATT = ws16 + OFF_ATT;
            ATT[((size_t)(b * TT + k)) * CC + h * DD + tid] = f2bf(o);
        }
    }
}

extern "C" void kernel_launch(void* const* d_in, const int* in_sizes, int n_in,
                              void* d_out, int out_size, void* d_ws, size_t ws_size,
                              hipStream_t stream) {
    u16* ws16 = (u16*)d_ws;

    dim3 gp(CC / 64, MM / 64, 5);   // 8 x 6 x 5
    proj5_kernel<<<gp, 256, 0, stream>>>(
        d_in[0], d_in[1], d_in[2], d_in[3], d_in[4], d_in[5], d_in[6],
        d_in[7], d_in[8], d_in[9], d_in[10], ws16);

    dim3 ga(TT / KG, BB * HH);      // 48 x 16, four k per block, 6 waves
    attn_kernel<<<ga, 384, 0, stream>>>(ws16);

    dim3 go(CC / 64, MM / 64, 1);   // 8 x 6
    projo_kernel<<<go, 256, 0, stream>>>(ws16, d_in[11], d_in[12], d_out, d_in[0]);
}

// Round 11
// 142.537 us; speedup vs baseline: 1.1490x; 1.0578x over previous
//
#include <hip/hip_runtime.h>
#include <hip/hip_bf16.h>

typedef unsigned short u16;
typedef unsigned int u32;

#define TT 192
#define BB 2
#define HH 8
#define DD 64
#define CC 512
#define MM (BB*TT)   // 384
#define KG 4         // k-values per attention block (768 blocks = 3/CU exact)

// ws layout (u16 elements): Q,K0,K1,V0,V1 each [bh][t][d], then ATT [m][c]
#define TSZ   ((size_t)MM * CC)
#define OFF_ATT (5 * TSZ)

typedef short bf16x8 __attribute__((ext_vector_type(8)));
typedef float f32x4  __attribute__((ext_vector_type(4)));

union FragU { uint4 u; bf16x8 b; };

// Raw HW transcendentals (r13-verified: VALUBusy 58->27%)
#if __has_builtin(__builtin_amdgcn_exp2f)
#define EXP2F(x) __builtin_amdgcn_exp2f(x)
#else
#define EXP2F(x) exp2f(x)
#endif
#if __has_builtin(__builtin_amdgcn_rcpf)
#define RCPF(x) __builtin_amdgcn_rcpf(x)
#else
#define RCPF(x) (1.f / (x))
#endif

__device__ __forceinline__ float bf2f(u16 u) {
    return __uint_as_float(((u32)u) << 16);
}
__device__ __forceinline__ u16 f2bf(float f) {
    u32 u = __float_as_uint(f);
    u32 r = u + 0x7FFFu + ((u >> 16) & 1u);   // RNE
    return (u16)(r >> 16);
}
// pack hi16(a),hi16(b) -> one u32 (truncation round; bias cancels in P/Z)
__device__ __forceinline__ u32 trunc_pk(u32 b_hi, u32 a_lo) {
    return __builtin_amdgcn_perm(b_hi, a_lo, 0x07060302u);
}

// dtype detect: 1 load + ballot. bf16 data => low u16 exponent near 127.
__device__ __forceinline__ u32 detect_bf16_fast(const u32* __restrict__ x) {
    const int lane = threadIdx.x & 63;
    u32 v = x[lane & 31];
    u32 e = (v >> 7) & 0xFF;
    unsigned long long m = __ballot(e >= 113 && e <= 133);
    return (__popcll(m) >= 32) ? 1u : 0u;
}

// dtype-aware 16-element load (two uint4 of packed bf16)
__device__ __forceinline__ void ld16(const void* __restrict__ base, size_t off, u32 fl,
                                     uint4& lo, uint4& hi) {
    if (fl) {
        const uint4* p = (const uint4*)((const u16*)base + off);
        lo = p[0]; hi = p[1];
    } else {
        const float* s = (const float*)base + off;
        float4 f0 = *(const float4*)(s);
        float4 f1 = *(const float4*)(s + 4);
        float4 f2 = *(const float4*)(s + 8);
        float4 f3 = *(const float4*)(s + 12);
        lo = make_uint4((u32)f2bf(f0.x) | ((u32)f2bf(f0.y) << 16),
                        (u32)f2bf(f0.z) | ((u32)f2bf(f0.w) << 16),
                        (u32)f2bf(f1.x) | ((u32)f2bf(f1.y) << 16),
                        (u32)f2bf(f1.z) | ((u32)f2bf(f1.w) << 16));
        hi = make_uint4((u32)f2bf(f2.x) | ((u32)f2bf(f2.y) << 16),
                        (u32)f2bf(f2.z) | ((u32)f2bf(f2.w) << 16),
                        (u32)f2bf(f3.x) | ((u32)f2bf(f3.y) << 16),
                        (u32)f2bf(f3.z) | ((u32)f2bf(f3.w) << 16));
    }
}

// ---------------------------------------------------------------------------
// LDS-staged MFMA projection GEMM (r9-verified): out = A @ W^T + bias.
// ---------------------------------------------------------------------------
__device__ __forceinline__ void proj_lds(const void* __restrict__ A, u32 aFl,
                                         const void* __restrict__ W,
                                         const void* __restrict__ bias, u32 wFl,
                                         void* __restrict__ out, int headperm, u32 outFl) {
    __shared__ __align__(16) u16 As[64][72];
    __shared__ __align__(16) u16 Ws[64][72];
    const int tid = threadIdx.x;
    const int w = tid >> 6, lane = tid & 63;
    const int quad = lane >> 4, li = lane & 15;
    const int mb = blockIdx.y * 64, nb = blockIdx.x * 64;

    const int r = tid >> 2;
    const int c = (tid & 3) * 16;

    const size_t abase = (size_t)(mb + r) * CC + c;
    const size_t wbase = (size_t)(nb + r) * CC + c;

    f32x4 acc[4];
#pragma unroll
    for (int ct = 0; ct < 4; ct++) acc[ct] = (f32x4){0.f, 0.f, 0.f, 0.f};

    uint4 a0, a1, w0, w1;
    ld16(A, abase, aFl, a0, a1);
    ld16(W, wbase, wFl, w0, w1);

#pragma unroll
    for (int step = 0; step < 8; step++) {
        *(uint4*)&As[r][c] = a0; *(uint4*)&As[r][c + 8] = a1;
        *(uint4*)&Ws[r][c] = w0; *(uint4*)&Ws[r][c + 8] = w1;
        __syncthreads();
        if (step < 7) {
            const int kb = (step + 1) * 64;
            ld16(A, abase + kb, aFl, a0, a1);
            ld16(W, wbase + kb, wFl, w0, w1);
        }
#pragma unroll
        for (int kk = 0; kk < 2; kk++) {
            FragU af; af.u = *(const uint4*)&As[w * 16 + li][kk * 32 + quad * 8];
#pragma unroll
            for (int ct = 0; ct < 4; ct++) {
                FragU wf; wf.u = *(const uint4*)&Ws[ct * 16 + li][kk * 32 + quad * 8];
                acc[ct] = __builtin_amdgcn_mfma_f32_16x16x32_bf16(af.b, wf.b, acc[ct], 0, 0, 0);
            }
        }
        __syncthreads();
    }

#pragma unroll
    for (int ct = 0; ct < 4; ct++) {
        const int n = nb + ct * 16 + li;
        const float bv = wFl ? bf2f(((const u16*)bias)[n]) : ((const float*)bias)[n];
#pragma unroll
        for (int rr = 0; rr < 4; rr++) {
            const int m = mb + w * 16 + quad * 4 + rr;
            const float v = acc[ct][rr] + bv;
            if (headperm) {
                const int b = (m >= TT) ? 1 : 0;
                const int tloc = m - b * TT;
                ((u16*)out)[((size_t)(b * HH + (n >> 6)) * TT + tloc) * DD + (n & 63)] = f2bf(v);
            } else {
                if (outFl) ((u16*)out)[(size_t)m * CC + n] = f2bf(v);
                else       ((float*)out)[(size_t)m * CC + n] = v;
            }
        }
    }
}

__global__ __launch_bounds__(256) void proj5_kernel(
    const void* __restrict__ x,
    const void* __restrict__ Wq,  const void* __restrict__ bq,
    const void* __restrict__ Wk0, const void* __restrict__ bk0,
    const void* __restrict__ Wk1, const void* __restrict__ bk1,
    const void* __restrict__ Wv0, const void* __restrict__ bv0,
    const void* __restrict__ Wv1, const void* __restrict__ bv1,
    u16* __restrict__ ws16) {
    const u32 fl = detect_bf16_fast((const u32*)x);
    const int z = blockIdx.z;
    const void* W; const void* bi;
    switch (z) {
        case 0:  W = Wq;  bi = bq;  break;
        case 1:  W = Wk0; bi = bk0; break;
        case 2:  W = Wk1; bi = bk1; break;
        case 3:  W = Wv0; bi = bv0; break;
        default: W = Wv1; bi = bv1; break;
    }
    proj_lds(x, fl, W, bi, fl, (void*)(ws16 + (size_t)z * TSZ), 1, 1u);
}

__global__ __launch_bounds__(256) void projo_kernel(const u16* __restrict__ ws16,
                                                    const void* __restrict__ Wo,
                                                    const void* __restrict__ bo,
                                                    void* __restrict__ out,
                                                    const void* __restrict__ xorig) {
    const u32 fl = detect_bf16_fast((const u32*)xorig);
    proj_lds(ws16 + OFF_ATT, 1u, Wo, bo, fl, out, 0, fl);
}

// ---------------------------------------------------------------------------
// MFMA attention, r24 (= r23 resubmitted after infra failure; code unchanged):
// r18 base (best measured: 44us, VGPR 124, 3 blocks/CU) + T5 s_setprio(1)
// around the MFMA clusters. Geometry space is exhausted (r18 44 < r19 52 <
// r22 55 < r13 60); register cliff blocks state growth (r20/r21); wave-
// thinning duplicates LDS fragment traffic (r22: conflicts x1.5). MFMA busy
// time (12.8us) already equals the arithmetic floor, so the remaining lever
// is issue ARBITRATION: waves on a SIMD come from different blocks at
// drifted phases (GEMM-heavy vs exp-heavy); setprio(1) during a wave's MFMA
// cluster wins issue slots vs co-resident exp/VALU waves (catalog T5/m191:
// +4-7% attn when phases diverge; null only in lockstep).
// Everything else byte-identical to r18.
// LDS: k1L 24576 + v1t 25600 + osum 2048 = 52224 B -> 3 blocks/CU.
// Pre-commit: null result => structural floor declared for this decomposition.
// ---------------------------------------------------------------------------
__global__ __launch_bounds__(256) void attn_kernel(u16* __restrict__ ws16) {
    __shared__ __align__(16) u16 k1L[TT * DD];      // 24576 B, XOR-swizzled
    __shared__ __align__(16) u16 v1t[DD * 200];     // 25600 B, r14 layout
    __shared__ float osum[2][256];                  // 2048 B, parity dbuf
    const int tid = threadIdx.x;
    const int w = tid >> 6, lane = tid & 63;
    const int quad = lane >> 4, li = lane & 15;
    const int kbase = blockIdx.x * KG, bh = blockIdx.y;

    const u16* qg0 = ws16 + ((size_t)bh * TT) * DD;
    const u16* k0g = ws16 + TSZ     + (size_t)bh * TT * DD;
    const u16* k1g = ws16 + 2 * TSZ + (size_t)bh * TT * DD;
    const u16* v0g = ws16 + 3 * TSZ + (size_t)bh * TT * DD;
    const u16* v1g = ws16 + 4 * TSZ + (size_t)bh * TT * DD;

    // ---- stage k1 (row-major, XOR swizzle: elem-col ^= (row&7)<<3) ----
#pragma unroll
    for (int it = 0; it < 6; it++) {
        const int flat = (it * 256 + tid) * 8;
        const int row = flat >> 6, c0 = flat & 63;
        uint4 b = *(const uint4*)(k1g + flat);
        *(uint4*)&k1L[row * DD + (c0 ^ ((row & 7) << 3))] = b;
    }

    // ---- stage v1^T (stride 200, conflict swz (pos>>3)^(d>>3)) with the
    //      K-slot permutation folded in: v1 row m -> pos bits {m3,m2,m4,m1,m0}
#pragma unroll
    for (int it = 0; it < 6; it++) {
        const int flat = (it * 256 + tid) * 8;
        const int row = flat >> 6, c0 = flat & 63;   // row=m, c0=d base
        uint4 b = *(const uint4*)(v1g + flat);
        u16 vb[8]; *(uint4*)vb = b;
        const int w5 = row & 31;
        const int pos = (row & ~31) | ((w5 & 12) << 1) | ((w5 >> 4) << 2) | (w5 & 3);
        const int swz = (((pos >> 3) ^ (c0 >> 3)) << 3) | (pos & 7);
#pragma unroll
        for (int j = 0; j < 8; j++)
            v1t[(c0 + j) * 200 + swz] = vb[j];
    }

    // ---- k-invariant k0 fragments (raw bf16, used to build afr per k) ----
    FragU k0f[3][2];
#pragma unroll
    for (int kk = 0; kk < 2; kk++)
#pragma unroll
        for (int rt = 0; rt < 3; rt++)
            k0f[rt][kk].u = *(const uint4*)(k0g + (size_t)(w * 48 + rt * 16 + li) * DD + kk * 32 + quad * 8);

    FragU ones;
    ones.u = make_uint4(0x3F803F80u, 0x3F803F80u, 0x3F803F80u, 0x3F803F80u);

    __syncthreads();   // k1L + v1t staged

    // ================= sequential k loop (KG k's per block) =================
#pragma unroll 1
    for (int kk6 = 0; kk6 < KG; kk6++) {
        const int k = kbase + kk6;

        // ---- afr: a[l,d] = bf16_trunc(scl*q[d]*k0[l,d]), scl=0.125*log2e ----
        FragU afr[3][2];
#pragma unroll
        for (int kk = 0; kk < 2; kk++) {
            uint4 qu = *(const uint4*)(qg0 + (size_t)k * DD + kk * 32 + quad * 8);
            u16 qv[8]; *(uint4*)qv = qu;
            float qf[8];
#pragma unroll
            for (int j = 0; j < 8; j++) qf[j] = bf2f(qv[j]) * 0.18033688f;
#pragma unroll
            for (int rt = 0; rt < 3; rt++) {
                u16 kv[8]; *(uint4*)kv = k0f[rt][kk].u;
                u32 pk[4];
#pragma unroll
                for (int p = 0; p < 4; p++) {
                    u32 lo = __float_as_uint(qf[2 * p] * bf2f(kv[2 * p]));
                    u32 hi = __float_as_uint(qf[2 * p + 1] * bf2f(kv[2 * p + 1]));
                    pk[p] = trunc_pk(hi, lo);
                }
                afr[rt][kk].u = make_uint4(pk[0], pk[1], pk[2], pk[3]);
            }
        }

        f32x4 Wacc[3][4], Zacc[3];
#pragma unroll
        for (int rt = 0; rt < 3; rt++) {
            Zacc[rt] = (f32x4){0.f, 0.f, 0.f, 0.f};
#pragma unroll
            for (int cd = 0; cd < 4; cd++) Wacc[rt][cd] = (f32x4){0.f, 0.f, 0.f, 0.f};
        }

        // ---- m-tile loop (6 x 32), barrier-free; kf from swizzled LDS ----
#pragma unroll
        for (int mt = 0; mt < 6; mt++) {
            FragU a2[3];
            // GEMM1: MFMA cluster under raised priority (T5)
#pragma unroll
            for (int ct = 0; ct < 2; ct++) {
                const int r0 = mt * 32 + ct * 16 + li;
                const int sw = (r0 & 7) << 3;
                FragU kf0, kf1;
                kf0.u = *(const uint4*)&k1L[r0 * DD + ((quad * 8) ^ sw)];
                kf1.u = *(const uint4*)&k1L[r0 * DD + ((32 + quad * 8) ^ sw)];
                __builtin_amdgcn_s_setprio(1);
                f32x4 acc0 = (f32x4){0.f, 0.f, 0.f, 0.f};
                f32x4 acc1 = (f32x4){0.f, 0.f, 0.f, 0.f};
                f32x4 acc2 = (f32x4){0.f, 0.f, 0.f, 0.f};
                acc0 = __builtin_amdgcn_mfma_f32_16x16x32_bf16(kf0.b, afr[0][0].b, acc0, 0, 0, 0);
                acc1 = __builtin_amdgcn_mfma_f32_16x16x32_bf16(kf0.b, afr[1][0].b, acc1, 0, 0, 0);
                acc2 = __builtin_amdgcn_mfma_f32_16x16x32_bf16(kf0.b, afr[2][0].b, acc2, 0, 0, 0);
                acc0 = __builtin_amdgcn_mfma_f32_16x16x32_bf16(kf1.b, afr[0][1].b, acc0, 0, 0, 0);
                acc1 = __builtin_amdgcn_mfma_f32_16x16x32_bf16(kf1.b, afr[1][1].b, acc1, 0, 0, 0);
                acc2 = __builtin_amdgcn_mfma_f32_16x16x32_bf16(kf1.b, afr[2][1].b, acc2, 0, 0, 0);
                __builtin_amdgcn_s_setprio(0);
                f32x4 accs[3] = {acc0, acc1, acc2};
#pragma unroll
                for (int rt = 0; rt < 3; rt++) {
                    const u32 lo = trunc_pk(__float_as_uint(EXP2F(accs[rt][1])), __float_as_uint(EXP2F(accs[rt][0])));
                    const u32 hi = trunc_pk(__float_as_uint(EXP2F(accs[rt][3])), __float_as_uint(EXP2F(accs[rt][2])));
                    if (ct == 0) { a2[rt].u.x = lo; a2[rt].u.y = hi; }
                    else         { a2[rt].u.z = lo; a2[rt].u.w = hi; }
                }
            }
            FragU b2[4];
#pragma unroll
            for (int cd = 0; cd < 4; cd++) {
                const int d = cd * 16 + li;
                b2[cd].u = *(const uint4*)&v1t[d * 200 + (((mt * 4 + quad) ^ (d >> 3)) << 3)];
            }
            // GEMM2 + Z: MFMA cluster under raised priority (T5)
            __builtin_amdgcn_s_setprio(1);
#pragma unroll
            for (int rt = 0; rt < 3; rt++) {
                Zacc[rt] = __builtin_amdgcn_mfma_f32_16x16x32_bf16(a2[rt].b, ones.b, Zacc[rt], 0, 0, 0);
#pragma unroll
                for (int cd = 0; cd < 4; cd++)
                    Wacc[rt][cd] = __builtin_amdgcn_mfma_f32_16x16x32_bf16(a2[rt].b, b2[cd].b, Wacc[rt][cd], 0, 0, 0);
            }
            __builtin_amdgcn_s_setprio(0);
        }

        // ---- epilogue: v0 from global (L2-hot), per-rt to cap live VGPRs ----
        float op[4] = {0.f, 0.f, 0.f, 0.f};
#pragma unroll
        for (int rt = 0; rt < 3; rt++) {
            float v0v[4][4];
#pragma unroll
            for (int r = 0; r < 4; r++) {
                const int l = w * 48 + rt * 16 + quad * 4 + r;
#pragma unroll
                for (int cd = 0; cd < 4; cd++)
                    v0v[r][cd] = bf2f(v0g[(size_t)l * DD + cd * 16 + li]);
            }
#pragma unroll
            for (int r = 0; r < 4; r++) {
                const float iv = RCPF(Zacc[rt][r]);
#pragma unroll
                for (int cd = 0; cd < 4; cd++)
                    op[cd] = fmaf(v0v[r][cd] * iv, Wacc[rt][cd][r], op[cd]);
            }
        }
#pragma unroll
        for (int cd = 0; cd < 4; cd++) {
            op[cd] += __shfl_xor(op[cd], 16);
            op[cd] += __shfl_xor(op[cd], 32);
        }
        float* os = osum[kk6 & 1];
        if (quad == 0) {
#pragma unroll
            for (int cd = 0; cd < 4; cd++) os[w * 64 + cd * 16 + li] = op[cd];
        }
        __syncthreads();
        if (tid < DD) {
            const float o = os[tid] + os[64 + tid] + os[128 + tid] + os[192 + tid];
            const int b = bh >> 3, h = bh & 7;
            u16* ATT = ws16 + OFF_ATT;
            ATT[((size_t)(b * TT + k)) * CC + h * DD + tid] = f2bf(o);
        }
    }
}

extern "C" void kernel_launch(void* const* d_in, const int* in_sizes, int n_in,
                              void* d_out, int out_size, void* d_ws, size_t ws_size,
                              hipStream_t stream) {
    u16* ws16 = (u16*)d_ws;

    dim3 gp(CC / 64, MM / 64, 5);   // 8 x 6 x 5
    proj5_kernel<<<gp, 256, 0, stream>>>(
        d_in[0], d_in[1], d_in[2], d_in[3], d_in[4], d_in[5], d_in[6],
        d_in[7], d_in[8], d_in[9], d_in[10], ws16);

    dim3 ga(TT / KG, BB * HH);      // 48 x 16, four k per block = 3 blocks/CU
    attn_kernel<<<ga, 256, 0, stream>>>(ws16);

    dim3 go(CC / 64, MM / 64, 1);   // 8 x 6
    projo_kernel<<<go, 256, 0, stream>>>(ws16, d_in[11], d_in[12], d_out, d_in[0]);
}

// Round 12
// 135.512 us; speedup vs baseline: 1.2086x; 1.0518x over previous
//
#include <hip/hip_runtime.h>
#include <hip/hip_bf16.h>

typedef unsigned short u16;
typedef unsigned int u32;

#define TT 192
#define BB 2
#define HH 8
#define DD 64
#define CC 512
#define MM (BB*TT)   // 384
#define KG 6         // k-values per attention block

// ws layout (u16 elements): Q,K0,K1,V0,V1 each [bh][t][d], then ATT [m][c]
#define TSZ   ((size_t)MM * CC)
#define OFF_ATT (5 * TSZ)

typedef short bf16x8 __attribute__((ext_vector_type(8)));
typedef float f32x4  __attribute__((ext_vector_type(4)));

union FragU { uint4 u; bf16x8 b; };

// Raw HW transcendentals (r13-verified: VALUBusy 58->27%)
#if __has_builtin(__builtin_amdgcn_exp2f)
#define EXP2F(x) __builtin_amdgcn_exp2f(x)
#else
#define EXP2F(x) exp2f(x)
#endif
#if __has_builtin(__builtin_amdgcn_rcpf)
#define RCPF(x) __builtin_amdgcn_rcpf(x)
#else
#define RCPF(x) (1.f / (x))
#endif

__device__ __forceinline__ float bf2f(u16 u) {
    return __uint_as_float(((u32)u) << 16);
}
__device__ __forceinline__ u16 f2bf(float f) {
    u32 u = __float_as_uint(f);
    u32 r = u + 0x7FFFu + ((u >> 16) & 1u);   // RNE
    return (u16)(r >> 16);
}
// pack hi16(a),hi16(b) -> one u32 (truncation round; bias cancels in P/Z)
__device__ __forceinline__ u32 trunc_pk(u32 b_hi, u32 a_lo) {
    return __builtin_amdgcn_perm(b_hi, a_lo, 0x07060302u);
}

// dtype detect: 1 load + ballot. bf16 data => low u16 exponent near 127.
__device__ __forceinline__ u32 detect_bf16_fast(const u32* __restrict__ x) {
    const int lane = threadIdx.x & 63;
    u32 v = x[lane & 31];
    u32 e = (v >> 7) & 0xFF;
    unsigned long long m = __ballot(e >= 113 && e <= 133);
    return (__popcll(m) >= 32) ? 1u : 0u;
}

// dtype-aware 16-element load (two uint4 of packed bf16)
__device__ __forceinline__ void ld16(const void* __restrict__ base, size_t off, u32 fl,
                                     uint4& lo, uint4& hi) {
    if (fl) {
        const uint4* p = (const uint4*)((const u16*)base + off);
        lo = p[0]; hi = p[1];
    } else {
        const float* s = (const float*)base + off;
        float4 f0 = *(const float4*)(s);
        float4 f1 = *(const float4*)(s + 4);
        float4 f2 = *(const float4*)(s + 8);
        float4 f3 = *(const float4*)(s + 12);
        lo = make_uint4((u32)f2bf(f0.x) | ((u32)f2bf(f0.y) << 16),
                        (u32)f2bf(f0.z) | ((u32)f2bf(f0.w) << 16),
                        (u32)f2bf(f1.x) | ((u32)f2bf(f1.y) << 16),
                        (u32)f2bf(f1.z) | ((u32)f2bf(f1.w) << 16));
        hi = make_uint4((u32)f2bf(f2.x) | ((u32)f2bf(f2.y) << 16),
                        (u32)f2bf(f2.z) | ((u32)f2bf(f2.w) << 16),
                        (u32)f2bf(f3.x) | ((u32)f2bf(f3.y) << 16),
                        (u32)f2bf(f3.z) | ((u32)f2bf(f3.w) << 16));
    }
}

// ---------------------------------------------------------------------------
// LDS-staged MFMA projection GEMM (r9-verified): out = A @ W^T + bias.
// ---------------------------------------------------------------------------
__device__ __forceinline__ void proj_lds(const void* __restrict__ A, u32 aFl,
                                         const void* __restrict__ W,
                                         const void* __restrict__ bias, u32 wFl,
                                         void* __restrict__ out, int headperm, u32 outFl) {
    __shared__ __align__(16) u16 As[64][72];
    __shared__ __align__(16) u16 Ws[64][72];
    const int tid = threadIdx.x;
    const int w = tid >> 6, lane = tid & 63;
    const int quad = lane >> 4, li = lane & 15;
    const int mb = blockIdx.y * 64, nb = blockIdx.x * 64;

    const int r = tid >> 2;
    const int c = (tid & 3) * 16;

    const size_t abase = (size_t)(mb + r) * CC + c;
    const size_t wbase = (size_t)(nb + r) * CC + c;

    f32x4 acc[4];
#pragma unroll
    for (int ct = 0; ct < 4; ct++) acc[ct] = (f32x4){0.f, 0.f, 0.f, 0.f};

    uint4 a0, a1, w0, w1;
    ld16(A, abase, aFl, a0, a1);
    ld16(W, wbase, wFl, w0, w1);

#pragma unroll
    for (int step = 0; step < 8; step++) {
        *(uint4*)&As[r][c] = a0; *(uint4*)&As[r][c + 8] = a1;
        *(uint4*)&Ws[r][c] = w0; *(uint4*)&Ws[r][c + 8] = w1;
        __syncthreads();
        if (step < 7) {
            const int kb = (step + 1) * 64;
            ld16(A, abase + kb, aFl, a0, a1);
            ld16(W, wbase + kb, wFl, w0, w1);
        }
#pragma unroll
        for (int kk = 0; kk < 2; kk++) {
            FragU af; af.u = *(const uint4*)&As[w * 16 + li][kk * 32 + quad * 8];
#pragma unroll
            for (int ct = 0; ct < 4; ct++) {
                FragU wf; wf.u = *(const uint4*)&Ws[ct * 16 + li][kk * 32 + quad * 8];
                acc[ct] = __builtin_amdgcn_mfma_f32_16x16x32_bf16(af.b, wf.b, acc[ct], 0, 0, 0);
            }
        }
        __syncthreads();
    }

#pragma unroll
    for (int ct = 0; ct < 4; ct++) {
        const int n = nb + ct * 16 + li;
        const float bv = wFl ? bf2f(((const u16*)bias)[n]) : ((const float*)bias)[n];
#pragma unroll
        for (int rr = 0; rr < 4; rr++) {
            const int m = mb + w * 16 + quad * 4 + rr;
            const float v = acc[ct][rr] + bv;
            if (headperm) {
                const int b = (m >= TT) ? 1 : 0;
                const int tloc = m - b * TT;
                ((u16*)out)[((size_t)(b * HH + (n >> 6)) * TT + tloc) * DD + (n & 63)] = f2bf(v);
            } else {
                if (outFl) ((u16*)out)[(size_t)m * CC + n] = f2bf(v);
                else       ((float*)out)[(size_t)m * CC + n] = v;
            }
        }
    }
}

__global__ __launch_bounds__(256) void proj5_kernel(
    const void* __restrict__ x,
    const void* __restrict__ Wq,  const void* __restrict__ bq,
    const void* __restrict__ Wk0, const void* __restrict__ bk0,
    const void* __restrict__ Wk1, const void* __restrict__ bk1,
    const void* __restrict__ Wv0, const void* __restrict__ bv0,
    const void* __restrict__ Wv1, const void* __restrict__ bv1,
    u16* __restrict__ ws16) {
    const u32 fl = detect_bf16_fast((const u32*)x);
    const int z = blockIdx.z;
    const void* W; const void* bi;
    switch (z) {
        case 0:  W = Wq;  bi = bq;  break;
        case 1:  W = Wk0; bi = bk0; break;
        case 2:  W = Wk1; bi = bk1; break;
        case 3:  W = Wv0; bi = bv0; break;
        default: W = Wv1; bi = bv1; break;
    }
    proj_lds(x, fl, W, bi, fl, (void*)(ws16 + (size_t)z * TSZ), 1, 1u);
}

__global__ __launch_bounds__(256) void projo_kernel(const u16* __restrict__ ws16,
                                                    const void* __restrict__ Wo,
                                                    const void* __restrict__ bo,
                                                    void* __restrict__ out,
                                                    const void* __restrict__ xorig) {
    const u32 fl = detect_bf16_fast((const u32*)xorig);
    proj_lds(ws16 + OFF_ATT, 1u, Wo, bo, fl, out, 0, fl);
}

// ---------------------------------------------------------------------------
// MFMA attention, FINAL (= r17, best measured: total 136.08us, attn <=42us).
// Session ledger (r14-r24):
//  - r17's multi-k + LDS-resident k1 was the one big win (60 -> 42us):
//    fix the STREAM (k1 re-read from global 4x/block, serialized vmcnt),
//    not the schedule. KG=6 (2 blocks/CU) beats KG=4 (3 blocks/CU): staging
//    amortization > occupancy (occupancy knobs measured dead, r14/r15/r18).
//  - Register window ~124 VGPR: caps lose ILP (r15), growth evicts blocks
//    (r20/r21). Per-k osum barrier is a needed live-range fence (r20).
//  - Wave-thinning duplicates LDS fragment traffic x1.5 (r19/r22). Lockstep
//    Z-exchange loses (r19). setprio null (r24). Compiler already hoists
//    maximally in the unrolled mt loop (r16 null).
// Structure: block=(bh, 6 k's), 4 waves x 48 l-rows; k1 staged once in LDS
// XOR-swizzled (conflict-free ds_read_b128); v1t scatter-staged with the
// m-permutation folded in so GEMM1's C-register layout IS GEMM2's A-fragment
// (register-resident P, zero cross-lane); k0 frags hoisted; sequential k
// loop with fresh accumulators per k; Z via mfma(P, ones).
// LDS: k1L 24576 + v1t 25600 + osum 2048 = 52224 B.
// Declared floor: MFMA busy (12.8us) = arithmetic floor; remainder is the
// GEMM1->exp->GEMM2 dependent chain at ~2-3 waves/SIMD; both escape routes
// (registers, waves) measured to fail. Remaining total is ~83us harness
// workspace-poison fills + ~11us projections (uncontrollable/minor).
// ---------------------------------------------------------------------------
__global__ __launch_bounds__(256) void attn_kernel(u16* __restrict__ ws16) {
    __shared__ __align__(16) u16 k1L[TT * DD];      // 24576 B, XOR-swizzled
    __shared__ __align__(16) u16 v1t[DD * 200];     // 25600 B, r14 layout
    __shared__ float osum[2][256];                  // 2048 B, parity dbuf
    const int tid = threadIdx.x;
    const int w = tid >> 6, lane = tid & 63;
    const int quad = lane >> 4, li = lane & 15;
    const int kbase = blockIdx.x * KG, bh = blockIdx.y;

    const u16* qg0 = ws16 + ((size_t)bh * TT) * DD;
    const u16* k0g = ws16 + TSZ     + (size_t)bh * TT * DD;
    const u16* k1g = ws16 + 2 * TSZ + (size_t)bh * TT * DD;
    const u16* v0g = ws16 + 3 * TSZ + (size_t)bh * TT * DD;
    const u16* v1g = ws16 + 4 * TSZ + (size_t)bh * TT * DD;

    // ---- stage k1 (row-major, XOR swizzle: elem-col ^= (row&7)<<3) ----
#pragma unroll
    for (int it = 0; it < 6; it++) {
        const int flat = (it * 256 + tid) * 8;
        const int row = flat >> 6, c0 = flat & 63;
        uint4 b = *(const uint4*)(k1g + flat);
        *(uint4*)&k1L[row * DD + (c0 ^ ((row & 7) << 3))] = b;
    }

    // ---- stage v1^T (stride 200, conflict swz (pos>>3)^(d>>3)) with the
    //      K-slot permutation folded in: v1 row m -> pos bits {m3,m2,m4,m1,m0}
#pragma unroll
    for (int it = 0; it < 6; it++) {
        const int flat = (it * 256 + tid) * 8;
        const int row = flat >> 6, c0 = flat & 63;   // row=m, c0=d base
        uint4 b = *(const uint4*)(v1g + flat);
        u16 vb[8]; *(uint4*)vb = b;
        const int w5 = row & 31;
        const int pos = (row & ~31) | ((w5 & 12) << 1) | ((w5 >> 4) << 2) | (w5 & 3);
        const int swz = (((pos >> 3) ^ (c0 >> 3)) << 3) | (pos & 7);
#pragma unroll
        for (int j = 0; j < 8; j++)
            v1t[(c0 + j) * 200 + swz] = vb[j];
    }

    // ---- k-invariant k0 fragments (raw bf16, used to build afr per k) ----
    FragU k0f[3][2];
#pragma unroll
    for (int kk = 0; kk < 2; kk++)
#pragma unroll
        for (int rt = 0; rt < 3; rt++)
            k0f[rt][kk].u = *(const uint4*)(k0g + (size_t)(w * 48 + rt * 16 + li) * DD + kk * 32 + quad * 8);

    FragU ones;
    ones.u = make_uint4(0x3F803F80u, 0x3F803F80u, 0x3F803F80u, 0x3F803F80u);

    __syncthreads();   // k1L + v1t staged

    // ================= sequential k loop (6 k's per block) =================
#pragma unroll 1
    for (int kk6 = 0; kk6 < KG; kk6++) {
        const int k = kbase + kk6;

        // ---- afr: a[l,d] = bf16_trunc(scl*q[d]*k0[l,d]), scl=0.125*log2e ----
        FragU afr[3][2];
#pragma unroll
        for (int kk = 0; kk < 2; kk++) {
            uint4 qu = *(const uint4*)(qg0 + (size_t)k * DD + kk * 32 + quad * 8);
            u16 qv[8]; *(uint4*)qv = qu;
            float qf[8];
#pragma unroll
            for (int j = 0; j < 8; j++) qf[j] = bf2f(qv[j]) * 0.18033688f;
#pragma unroll
            for (int rt = 0; rt < 3; rt++) {
                u16 kv[8]; *(uint4*)kv = k0f[rt][kk].u;
                u32 pk[4];
#pragma unroll
                for (int p = 0; p < 4; p++) {
                    u32 lo = __float_as_uint(qf[2 * p] * bf2f(kv[2 * p]));
                    u32 hi = __float_as_uint(qf[2 * p + 1] * bf2f(kv[2 * p + 1]));
                    pk[p] = trunc_pk(hi, lo);
                }
                afr[rt][kk].u = make_uint4(pk[0], pk[1], pk[2], pk[3]);
            }
        }

        f32x4 Wacc[3][4], Zacc[3];
#pragma unroll
        for (int rt = 0; rt < 3; rt++) {
            Zacc[rt] = (f32x4){0.f, 0.f, 0.f, 0.f};
#pragma unroll
            for (int cd = 0; cd < 4; cd++) Wacc[rt][cd] = (f32x4){0.f, 0.f, 0.f, 0.f};
        }

        // ---- m-tile loop (6 x 32), barrier-free; kf from swizzled LDS ----
#pragma unroll
        for (int mt = 0; mt < 6; mt++) {
            FragU a2[3];
#pragma unroll
            for (int ct = 0; ct < 2; ct++) {
                const int r0 = mt * 32 + ct * 16 + li;
                const int sw = (r0 & 7) << 3;
                FragU kf0, kf1;
                kf0.u = *(const uint4*)&k1L[r0 * DD + ((quad * 8) ^ sw)];
                kf1.u = *(const uint4*)&k1L[r0 * DD + ((32 + quad * 8) ^ sw)];
#pragma unroll
                for (int rt = 0; rt < 3; rt++) {
                    f32x4 acc = (f32x4){0.f, 0.f, 0.f, 0.f};
                    acc = __builtin_amdgcn_mfma_f32_16x16x32_bf16(kf0.b, afr[rt][0].b, acc, 0, 0, 0);
                    acc = __builtin_amdgcn_mfma_f32_16x16x32_bf16(kf1.b, afr[rt][1].b, acc, 0, 0, 0);
                    const u32 lo = trunc_pk(__float_as_uint(EXP2F(acc[1])), __float_as_uint(EXP2F(acc[0])));
                    const u32 hi = trunc_pk(__float_as_uint(EXP2F(acc[3])), __float_as_uint(EXP2F(acc[2])));
                    if (ct == 0) { a2[rt].u.x = lo; a2[rt].u.y = hi; }
                    else         { a2[rt].u.z = lo; a2[rt].u.w = hi; }
                }
            }
            FragU b2[4];
#pragma unroll
            for (int cd = 0; cd < 4; cd++) {
                const int d = cd * 16 + li;
                b2[cd].u = *(const uint4*)&v1t[d * 200 + (((mt * 4 + quad) ^ (d >> 3)) << 3)];
            }
#pragma unroll
            for (int rt = 0; rt < 3; rt++) {
                Zacc[rt] = __builtin_amdgcn_mfma_f32_16x16x32_bf16(a2[rt].b, ones.b, Zacc[rt], 0, 0, 0);
#pragma unroll
                for (int cd = 0; cd < 4; cd++)
                    Wacc[rt][cd] = __builtin_amdgcn_mfma_f32_16x16x32_bf16(a2[rt].b, b2[cd].b, Wacc[rt][cd], 0, 0, 0);
            }
        }

        // ---- epilogue: v0 from global (L2-hot), per-rt to cap live VGPRs ----
        float op[4] = {0.f, 0.f, 0.f, 0.f};
#pragma unroll
        for (int rt = 0; rt < 3; rt++) {
            float v0v[4][4];
#pragma unroll
            for (int r = 0; r < 4; r++) {
                const int l = w * 48 + rt * 16 + quad * 4 + r;
#pragma unroll
                for (int cd = 0; cd < 4; cd++)
                    v0v[r][cd] = bf2f(v0g[(size_t)l * DD + cd * 16 + li]);
            }
#pragma unroll
            for (int r = 0; r < 4; r++) {
                const float iv = RCPF(Zacc[rt][r]);
#pragma unroll
                for (int cd = 0; cd < 4; cd++)
                    op[cd] = fmaf(v0v[r][cd] * iv, Wacc[rt][cd][r], op[cd]);
            }
        }
#pragma unroll
        for (int cd = 0; cd < 4; cd++) {
            op[cd] += __shfl_xor(op[cd], 16);
            op[cd] += __shfl_xor(op[cd], 32);
        }
        float* os = osum[kk6 & 1];
        if (quad == 0) {
#pragma unroll
            for (int cd = 0; cd < 4; cd++) os[w * 64 + cd * 16 + li] = op[cd];
        }
        __syncthreads();
        if (tid < DD) {
            const float o = os[tid] + os[64 + tid] + os[128 + tid] + os[192 + tid];
            const int b = bh >> 3, h = bh & 7;
            u16* ATT = ws16 + OFF_ATT;
            ATT[((size_t)(b * TT + k)) * CC + h * DD + tid] = f2bf(o);
        }
    }
}

extern "C" void kernel_launch(void* const* d_in, const int* in_sizes, int n_in,
                              void* d_out, int out_size, void* d_ws, size_t ws_size,
                              hipStream_t stream) {
    u16* ws16 = (u16*)d_ws;

    dim3 gp(CC / 64, MM / 64, 5);   // 8 x 6 x 5
    proj5_kernel<<<gp, 256, 0, stream>>>(
        d_in[0], d_in[1], d_in[2], d_in[3], d_in[4], d_in[5], d_in[6],
        d_in[7], d_in[8], d_in[9], d_in[10], ws16);

    dim3 ga(TT / KG, BB * HH);      // 32 x 16, six k per block
    attn_kernel<<<ga, 256, 0, stream>>>(ws16);

    dim3 go(CC / 64, MM / 64, 1);   // 8 x 6
    projo_kernel<<<go, 256, 0, stream>>>(ws16, d_in[11], d_in[12], d_out, d_in[0]);
}